// Round 2
// baseline (214.976 us; speedup 1.0000x reference)
//
#include <hip/hip_runtime.h>
#include <hip/hip_bf16.h>
#include <math.h>

typedef __bf16 bf16;
typedef __bf16 bf16x4 __attribute__((ext_vector_type(4)));
typedef __bf16 bf16x8 __attribute__((ext_vector_type(8)));
typedef float f32x4 __attribute__((ext_vector_type(4)));
typedef unsigned short ushort8 __attribute__((ext_vector_type(8)));

#define MFMA16(a, b, c) __builtin_amdgcn_mfma_f32_16x16x32_bf16(a, b, c, 0, 0, 0)
#define BAR_LGKM() asm volatile("s_waitcnt lgkmcnt(0)\n\ts_barrier" ::: "memory")

__device__ inline bf16x8 frag2(bf16x4 a, bf16x4 b) {
    bf16x8 r;
    r[0] = a[0]; r[1] = a[1]; r[2] = a[2]; r[3] = a[3];
    r[4] = b[0]; r[5] = b[1]; r[6] = b[2]; r[7] = b[3];
    return r;
}

__device__ inline bf16x8 frag_from(const bf16* p0, const bf16* p1) {
    return frag2(*(const bf16x4*)p0, *(const bf16x4*)p1);
}

// ---------------------------------------------------------------------------
// Kernel 1: QKV projections.  out[i][o] = sum_c in[c][i] * W[o][c] + b[o]
// ---------------------------------------------------------------------------
__global__ __launch_bounds__(256) void k_qkv(
    const float* __restrict__ x, const float* __restrict__ y,
    const float* __restrict__ Wq, const float* __restrict__ bq,
    const float* __restrict__ Wk, const float* __restrict__ bk,
    const float* __restrict__ Wv, const float* __restrict__ bv,
    bf16* __restrict__ Qo, bf16* __restrict__ Ko, bf16* __restrict__ Vo)
{
    const int zi = blockIdx.z;
    const float* src  = (zi == 0) ? x : y;
    const float* W    = (zi == 0) ? Wq : (zi == 1 ? Wk : Wv);
    const float* bias = (zi == 0) ? bq : (zi == 1 ? bk : bv);
    bf16* dst         = (zi == 0) ? Qo : (zi == 1 ? Ko : Vo);

    const int i0 = blockIdx.x * 64;
    const int o0 = blockIdx.y * 64;
    const int t = threadIdx.x;
    const int lane = t & 63;
    const int w = t >> 6;
    const int wr = w >> 1, wc = w & 1;
    const int l16 = lane & 15, lg = lane >> 4;

    __shared__ bf16 As[64][40];   // [m][k]
    __shared__ bf16 Bs[64][40];   // [n][k]

    f32x4 acc[2][2] = {};

    for (int kc = 0; kc < 256; kc += 32) {
        __syncthreads();
        for (int p = 0; p < 2; ++p) {
            int e = t + 256 * p;          // 0..511
            int c = e >> 4, m0 = (e & 15) * 4;
            f32x4 v = *(const f32x4*)&src[(kc + c) * 4096 + i0 + m0];
            for (int j = 0; j < 4; ++j) As[m0 + j][c] = (bf16)v[j];
        }
        for (int p = 0; p < 2; ++p) {
            int e = t + 256 * p;
            int n = e >> 3, c0 = (e & 7) * 4;
            f32x4 v = *(const f32x4*)&W[(o0 + n) * 256 + kc + c0];
            bf16x4 b;
            for (int j = 0; j < 4; ++j) b[j] = (bf16)v[j];
            *(bf16x4*)&Bs[n][c0] = b;
        }
        __syncthreads();
        const int c0 = 4 * lg;
        bf16x8 af[2], bfr[2];
        for (int mi = 0; mi < 2; ++mi) {
            int m = 32 * wr + 16 * mi + l16;
            af[mi] = frag_from(&As[m][c0], &As[m][c0 + 16]);
        }
        for (int ni = 0; ni < 2; ++ni) {
            int n = 32 * wc + 16 * ni + l16;
            bfr[ni] = frag_from(&Bs[n][c0], &Bs[n][c0 + 16]);
        }
        for (int mi = 0; mi < 2; ++mi)
            for (int ni = 0; ni < 2; ++ni)
                acc[mi][ni] = MFMA16(af[mi], bfr[ni], acc[mi][ni]);
    }

    for (int mi = 0; mi < 2; ++mi)
        for (int ni = 0; ni < 2; ++ni) {
            int n = o0 + 32 * wc + 16 * ni + l16;
            float bv_ = bias[n];
            for (int i = 0; i < 4; ++i) {
                int m = i0 + 32 * wr + 16 * mi + 4 * lg + i;
                dst[m * 256 + n] = (bf16)(acc[mi][ni][i] + bv_);
            }
        }
}

// ---------------------------------------------------------------------------
// Kernel T: transpose V [4096][256] -> Vt [256][4096] (bf16)
// ---------------------------------------------------------------------------
__global__ __launch_bounds__(256) void k_transpose(
    const bf16* __restrict__ V, bf16* __restrict__ Vt)
{
    __shared__ bf16 tile[32][33];
    const int i0 = blockIdx.x * 32;
    const int o0 = blockIdx.y * 32;
    const int t = threadIdx.x;
    for (int p = 0; p < 4; ++p) {
        int e = t + 256 * p;
        int r = e >> 5, c = e & 31;
        tile[r][c] = V[(i0 + r) * 256 + o0 + c];
    }
    __syncthreads();
    for (int p = 0; p < 4; ++p) {
        int e = t + 256 * p;
        int r = e >> 5, c = e & 31;
        Vt[(o0 + r) * 4096 + i0 + c] = tile[c][r];
    }
}

// ---------------------------------------------------------------------------
// Kernel 2: flash attention, BQ=16, KV split in 2 halves (flash-decoding).
// K double-buffered in LDS (reg-staged, issue-early/write-late), V read
// directly from global Vt (L2-resident). Barriers are lgkmcnt-only so global
// loads stay in flight across them.
// Outputs: Ot[split][q][d] = normalized partial O (bf16); stats m/l per row.
// ---------------------------------------------------------------------------
__global__ __launch_bounds__(256, 2) void k_flash(
    const bf16* __restrict__ Qg, const bf16* __restrict__ Kg,
    const bf16* __restrict__ Vtg, bf16* __restrict__ Ot,
    float* __restrict__ statm, float* __restrict__ statl)
{
    __shared__ char  Ks[2][32768];    // 64 keys x 512B, XOR-swizzled rows
    __shared__ float S_lds[16][73];
    __shared__ bf16  P_lds[16][68];
    __shared__ float m_l[16], l_l[16], corr_l[16];

    const int t = threadIdx.x;
    const int lane = t & 63;
    const int w = t >> 6;
    const int l16 = lane & 15, lg = lane >> 4;
    const int q0 = blockIdx.x * 16;
    const int split = blockIdx.y;
    const int kbase = split * 2048;
    const int NT = 32;                 // 2048 / 64

    // Q fragments straight from global (one-time)
    bf16x8 Qf[8];
    for (int ks = 0; ks < 8; ++ks) {
        int col = 32 * ks + 4 * lg;
        const bf16* qp = Qg + (q0 + l16) * 256 + col;
        Qf[ks] = frag2(*(const bf16x4*)qp, *(const bf16x4*)(qp + 16));
    }
    if (t < 16) { m_l[t] = -1e30f; l_l[t] = 0.f; }

    // prologue: load + write K tile 0
    ushort8 kreg[8];
    {
        for (int p = 0; p < 8; ++p) {
            int e = t + 256 * p;
            int r = e >> 5, u = e & 31;
            kreg[p] = *(const ushort8*)(Kg + (kbase + r) * 256 + 8 * u);
        }
        for (int p = 0; p < 8; ++p) {
            int e = t + 256 * p;
            int r = e >> 5, u = e & 31;
            *(ushort8*)&Ks[0][r * 512 + ((u * 16) ^ ((r & 7) << 4))] = kreg[p];
        }
    }

    f32x4 O[4] = {};                   // [ni]: rows 4lg+i, cols 64w+16ni+l16
    int cur = 0;

    for (int tt = 0; tt < NT; ++tt) {
        const int kv = kbase + tt * 64;
        if (tt < NT - 1) {             // issue next K tile early
            for (int p = 0; p < 8; ++p) {
                int e = t + 256 * p;
                int r = e >> 5, u = e & 31;
                kreg[p] = *(const ushort8*)(Kg + (kv + 64 + r) * 256 + 8 * u);
            }
        }
        BAR_LGKM();                    // K[cur] visible

        // QK^T: this wave owns keys [16w, 16w+16)
        {
            f32x4 S = {};
            int key = 16 * w + l16;
            int rb = key * 512, sw = (key & 7) << 4;
            const char* kc_ = &Ks[cur][0];
            for (int ks = 0; ks < 8; ++ks) {
                int db0 = 64 * ks + 8 * lg;
                bf16x4 b0 = *(const bf16x4*)&kc_[rb + (db0 ^ sw)];
                bf16x4 b1 = *(const bf16x4*)&kc_[rb + ((db0 + 32) ^ sw)];
                S = MFMA16(Qf[ks], frag2(b0, b1), S);
            }
            for (int i = 0; i < 4; ++i)
                S_lds[4 * lg + i][16 * w + l16] = S[i] * 0.0625f;
        }
        BAR_LGKM();

        // online softmax: 16 threads per row, 4 cols each
        {
            int r = t >> 4, c0 = (t & 15) * 4;
            float s[4];
            float mx = -1e30f;
            for (int j = 0; j < 4; ++j) { s[j] = S_lds[r][c0 + j]; mx = fmaxf(mx, s[j]); }
            mx = fmaxf(mx, __shfl_xor(mx, 1));
            mx = fmaxf(mx, __shfl_xor(mx, 2));
            mx = fmaxf(mx, __shfl_xor(mx, 4));
            mx = fmaxf(mx, __shfl_xor(mx, 8));
            float mo = m_l[r];
            float mn = fmaxf(mo, mx);
            float sum = 0.f;
            for (int j = 0; j < 4; ++j) { float p_ = __expf(s[j] - mn); s[j] = p_; sum += p_; }
            sum += __shfl_xor(sum, 1);
            sum += __shfl_xor(sum, 2);
            sum += __shfl_xor(sum, 4);
            sum += __shfl_xor(sum, 8);
            if ((t & 15) == 0) {
                float corr = __expf(mo - mn);
                l_l[r] = l_l[r] * corr + sum;
                m_l[r] = mn;
                corr_l[r] = corr;
            }
            for (int j = 0; j < 4; ++j) P_lds[r][c0 + j] = (bf16)s[j];
        }
        BAR_LGKM();

        if (tt < NT - 1) {             // write next K tile into other buffer
            for (int p = 0; p < 8; ++p) {
                int e = t + 256 * p;
                int r = e >> 5, u = e & 31;
                *(ushort8*)&Ks[cur ^ 1][r * 512 + ((u * 16) ^ ((r & 7) << 4))] = kreg[p];
            }
        }

        // O rescale + O += P @ V  (V fragments from global Vt, L2-resident)
        {
            float cr[4];
            for (int i = 0; i < 4; ++i) cr[i] = corr_l[4 * lg + i];
            for (int ni = 0; ni < 4; ++ni)
                for (int i = 0; i < 4; ++i)
                    O[ni][i] *= cr[i];
            for (int ks2 = 0; ks2 < 2; ++ks2) {
                int k0 = 32 * ks2 + 4 * lg;
                bf16x8 pa = frag_from(&P_lds[l16][k0], &P_lds[l16][k0 + 16]);
                for (int ni = 0; ni < 4; ++ni) {
                    int d = 64 * w + 16 * ni + l16;
                    const bf16* vp = Vtg + d * 4096 + kv + k0;
                    bf16x8 vb = frag2(*(const bf16x4*)vp, *(const bf16x4*)(vp + 16));
                    O[ni] = MFMA16(pa, vb, O[ni]);
                }
            }
        }
        cur ^= 1;
    }

    __syncthreads();
    float linv[4];
    for (int i = 0; i < 4; ++i) linv[i] = 1.f / l_l[4 * lg + i];
    for (int ni = 0; ni < 4; ++ni)
        for (int i = 0; i < 4; ++i) {
            int q = split * 4096 + q0 + 4 * lg + i;
            int d = 64 * w + 16 * ni + l16;
            Ot[q * 256 + d] = (bf16)(O[ni][i] * linv[i]);
        }
    if (t < 16) {
        statm[split * 4096 + q0 + t] = m_l[t];
        statl[split * 4096 + q0 + t] = l_l[t];
    }
}

// ---------------------------------------------------------------------------
// Kernel M: merge the 2 KV-splits. att = c0*O0 + c1*O1
// ---------------------------------------------------------------------------
__global__ __launch_bounds__(256) void k_merge(
    const bf16* __restrict__ Ot, const float* __restrict__ statm,
    const float* __restrict__ statl, bf16* __restrict__ att)
{
    const int t = threadIdx.x;
    const int q = blockIdx.x * 16 + (t >> 4);
    const int d0 = (t & 15) * 16;
    float m0 = statm[q], m1 = statm[4096 + q];
    float l0 = statl[q], l1 = statl[4096 + q];
    float M = fmaxf(m0, m1);
    float a0 = __expf(m0 - M) * l0, a1 = __expf(m1 - M) * l1;
    float inv = 1.f / (a0 + a1);
    float c0 = a0 * inv, c1 = a1 * inv;
    for (int h = 0; h < 2; ++h) {
        bf16x8 v0 = *(const bf16x8*)(Ot + q * 256 + d0 + 8 * h);
        bf16x8 v1 = *(const bf16x8*)(Ot + (4096 + q) * 256 + d0 + 8 * h);
        bf16x8 o;
        for (int j = 0; j < 8; ++j)
            o[j] = (bf16)(c0 * (float)v0[j] + c1 * (float)v1[j]);
        *(bf16x8*)(att + q * 256 + d0 + 8 * h) = o;
    }
}

// ---------------------------------------------------------------------------
// Kernel 3: z = att @ Wo^T + bo, then channel LayerNorm. BM=16, grid 256.
// ---------------------------------------------------------------------------
__global__ __launch_bounds__(256) void k_proj_ln(
    const bf16* __restrict__ att, const float* __restrict__ Wo,
    const float* __restrict__ bo, const float* __restrict__ ln_w,
    const float* __restrict__ ln_b, bf16* __restrict__ zn)
{
    __shared__ bf16 As[16][40];
    __shared__ bf16 Bs[256][40];
    __shared__ float psum[4][16], psq[4][16];
    __shared__ float mean_l[16], inv_l[16];

    const int t = threadIdx.x, lane = t & 63, w = t >> 6;
    const int l16 = lane & 15, lg = lane >> 4;
    const int q0 = blockIdx.x * 16;

    f32x4 acc[4] = {};
    for (int kc = 0; kc < 256; kc += 32) {
        __syncthreads();
        if (t < 64) {
            int r = t >> 2, u = t & 3;
            ushort8 v = *(const ushort8*)(att + (q0 + r) * 256 + kc + 8 * u);
            *(ushort8*)((char*)&As[r][0] + 16 * u) = v;
        }
        for (int p = 0; p < 8; ++p) {
            int e = t + 256 * p;          // 0..2047
            int n = e >> 3, c0 = (e & 7) * 4;
            f32x4 v = *(const f32x4*)&Wo[n * 256 + kc + c0];
            bf16x4 b;
            for (int j = 0; j < 4; ++j) b[j] = (bf16)v[j];
            *(bf16x4*)&Bs[n][c0] = b;
        }
        __syncthreads();
        bf16x8 af = frag_from(&As[l16][4 * lg], &As[l16][4 * lg + 16]);
        for (int ni = 0; ni < 4; ++ni) {
            int n = 64 * w + 16 * ni + l16;
            bf16x8 bfr = frag_from(&Bs[n][4 * lg], &Bs[n][4 * lg + 16]);
            acc[ni] = MFMA16(af, bfr, acc[ni]);
        }
    }

    float z[4][4];
    float rs[4] = {}, rq[4] = {};
    for (int ni = 0; ni < 4; ++ni) {
        int n = 64 * w + 16 * ni + l16;
        float b_ = bo[n];
        for (int i = 0; i < 4; ++i) {
            float v = acc[ni][i] + b_;
            z[ni][i] = v;
            rs[i] += v;
            rq[i] += v * v;
        }
    }
    for (int i = 0; i < 4; ++i) {
        float s = rs[i], q = rq[i];
        for (int msk = 1; msk <= 8; msk <<= 1) {
            s += __shfl_xor(s, msk);
            q += __shfl_xor(q, msk);
        }
        if (l16 == 0) { psum[w][4 * lg + i] = s; psq[w][4 * lg + i] = q; }
    }
    __syncthreads();
    if (t < 16) {
        float s = psum[0][t] + psum[1][t] + psum[2][t] + psum[3][t];
        float q = psq[0][t] + psq[1][t] + psq[2][t] + psq[3][t];
        float mean = s * (1.f / 256.f);
        float var = q * (1.f / 256.f) - mean * mean;
        mean_l[t] = mean;
        inv_l[t] = rsqrtf(var + 1e-6f);
    }
    __syncthreads();
    for (int ni = 0; ni < 4; ++ni) {
        int n = 64 * w + 16 * ni + l16;
        float g = ln_w[n], be = ln_b[n];
        for (int i = 0; i < 4; ++i) {
            int r = 4 * lg + i;
            float v = (z[ni][i] - mean_l[r]) * inv_l[r] * g + be;
            zn[(q0 + r) * 256 + n] = (bf16)v;
        }
    }
}

// ---------------------------------------------------------------------------
// Kernel 4: t1 = gelu(zn @ W1^T + b1)
// ---------------------------------------------------------------------------
__global__ __launch_bounds__(256) void k_mlp1(
    const bf16* __restrict__ zn, const float* __restrict__ W1,
    const float* __restrict__ b1, bf16* __restrict__ t1)
{
    __shared__ bf16 As[64][40];
    __shared__ bf16 Bs[64][40];
    const int t = threadIdx.x, lane = t & 63, w = t >> 6;
    const int l16 = lane & 15, lg = lane >> 4;
    const int wr = w >> 1, wc = w & 1;
    const int i0 = blockIdx.x * 64, n0 = blockIdx.y * 64;
    f32x4 acc[2][2] = {};
    for (int kc = 0; kc < 256; kc += 32) {
        __syncthreads();
        {
            int r = t >> 2, u = t & 3;
            ushort8 v = *(const ushort8*)(zn + (i0 + r) * 256 + kc + 8 * u);
            *(ushort8*)((char*)&As[r][0] + 16 * u) = v;
        }
        for (int p = 0; p < 2; ++p) {
            int e = t + 256 * p;
            int n = e >> 3, c0 = (e & 7) * 4;
            f32x4 v = *(const f32x4*)&W1[(n0 + n) * 256 + kc + c0];
            bf16x4 b;
            for (int j = 0; j < 4; ++j) b[j] = (bf16)v[j];
            *(bf16x4*)&Bs[n][c0] = b;
        }
        __syncthreads();
        bf16x8 af[2], bfr[2];
        for (int mi = 0; mi < 2; ++mi) {
            int m = 32 * wr + 16 * mi + l16;
            af[mi] = frag_from(&As[m][4 * lg], &As[m][4 * lg + 16]);
        }
        for (int ni = 0; ni < 2; ++ni) {
            int n = 32 * wc + 16 * ni + l16;
            bfr[ni] = frag_from(&Bs[n][4 * lg], &Bs[n][4 * lg + 16]);
        }
        for (int mi = 0; mi < 2; ++mi)
            for (int ni = 0; ni < 2; ++ni)
                acc[mi][ni] = MFMA16(af[mi], bfr[ni], acc[mi][ni]);
    }
    for (int ni = 0; ni < 2; ++ni) {
        int n = n0 + 32 * wc + 16 * ni + l16;
        float b_ = b1[n];
        for (int mi = 0; mi < 2; ++mi)
            for (int i = 0; i < 4; ++i) {
                int m = i0 + 32 * wr + 16 * mi + 4 * lg + i;
                float h = acc[mi][ni][i] + b_;
                float g = 0.5f * h * (1.f + erff(h * 0.70710678118f));
                t1[m * 512 + n] = (bf16)g;
            }
    }
}

// ---------------------------------------------------------------------------
// Kernel 5: t = t1 @ W2^T + b2; out[c][i] = x[c][i] + t[i][c]
// ---------------------------------------------------------------------------
__global__ __launch_bounds__(256) void k_mlp2(
    const bf16* __restrict__ t1, const float* __restrict__ W2,
    const float* __restrict__ b2, const float* __restrict__ x,
    float* __restrict__ out)
{
    __shared__ bf16 As[64][40];
    __shared__ bf16 Bs[64][40];
    __shared__ float T[64][65];
    const int t = threadIdx.x, lane = t & 63, w = t >> 6;
    const int l16 = lane & 15, lg = lane >> 4;
    const int wr = w >> 1, wc = w & 1;
    const int i0 = blockIdx.x * 64, n0 = blockIdx.y * 64;
    f32x4 acc[2][2] = {};
    for (int kc = 0; kc < 512; kc += 32) {
        __syncthreads();
        {
            int r = t >> 2, u = t & 3;
            ushort8 v = *(const ushort8*)(t1 + (i0 + r) * 512 + kc + 8 * u);
            *(ushort8*)((char*)&As[r][0] + 16 * u) = v;
        }
        for (int p = 0; p < 2; ++p) {
            int e = t + 256 * p;
            int n = e >> 3, c0 = (e & 7) * 4;
            f32x4 v = *(const f32x4*)&W2[(n0 + n) * 512 + kc + c0];
            bf16x4 b;
            for (int j = 0; j < 4; ++j) b[j] = (bf16)v[j];
            *(bf16x4*)&Bs[n][c0] = b;
        }
        __syncthreads();
        bf16x8 af[2], bfr[2];
        for (int mi = 0; mi < 2; ++mi) {
            int m = 32 * wr + 16 * mi + l16;
            af[mi] = frag_from(&As[m][4 * lg], &As[m][4 * lg + 16]);
        }
        for (int ni = 0; ni < 2; ++ni) {
            int n = 32 * wc + 16 * ni + l16;
            bfr[ni] = frag_from(&Bs[n][4 * lg], &Bs[n][4 * lg + 16]);
        }
        for (int mi = 0; mi < 2; ++mi)
            for (int ni = 0; ni < 2; ++ni)
                acc[mi][ni] = MFMA16(af[mi], bfr[ni], acc[mi][ni]);
    }
    for (int ni = 0; ni < 2; ++ni) {
        int nn = 32 * wc + 16 * ni + l16;
        float b_ = b2[n0 + nn];
        for (int mi = 0; mi < 2; ++mi)
            for (int i = 0; i < 4; ++i) {
                int mloc = 32 * wr + 16 * mi + 4 * lg + i;
                T[nn][mloc] = acc[mi][ni][i] + b_;
            }
    }
    __syncthreads();
    for (int p = 0; p < 16; ++p) {
        int e = t + 256 * p;
        int nn = e >> 6, mm = e & 63;
        int c = n0 + nn, m = i0 + mm;
        out[c * 4096 + m] = x[c * 4096 + m] + T[nn][mm];
    }
}

// ---------------------------------------------------------------------------
extern "C" void kernel_launch(void* const* d_in, const int* in_sizes, int n_in,
                              void* d_out, int out_size, void* d_ws, size_t ws_size,
                              hipStream_t stream) {
    (void)in_sizes; (void)n_in; (void)out_size; (void)ws_size;
    const float* x   = (const float*)d_in[0];
    const float* y   = (const float*)d_in[1];
    const float* Wq  = (const float*)d_in[2];
    const float* bq  = (const float*)d_in[3];
    const float* Wk  = (const float*)d_in[4];
    const float* bk  = (const float*)d_in[5];
    const float* Wv  = (const float*)d_in[6];
    const float* bv  = (const float*)d_in[7];
    const float* Wo  = (const float*)d_in[8];
    const float* bo  = (const float*)d_in[9];
    const float* lnw = (const float*)d_in[10];
    const float* lnb = (const float*)d_in[11];
    const float* W1  = (const float*)d_in[12];
    const float* b1  = (const float*)d_in[13];
    const float* W2  = (const float*)d_in[14];
    const float* b2  = (const float*)d_in[15];
    float* out = (float*)d_out;

    char* ws = (char*)d_ws;
    const size_t MB2 = 1u << 21;
    bf16*  Qb    = (bf16*)(ws + 0 * MB2);
    bf16*  Kb    = (bf16*)(ws + 1 * MB2);
    bf16*  Vb    = (bf16*)(ws + 2 * MB2);   // dead after k_transpose
    float* stats = (float*)(ws + 2 * MB2);  // reuses Vb region: [2][4096] m, [2][4096] l
    bf16*  Vt    = (bf16*)(ws + 3 * MB2);
    bf16*  att   = (bf16*)(ws + 4 * MB2);
    bf16*  zn    = (bf16*)(ws + 5 * MB2);
    bf16*  Ot    = (bf16*)(ws + 6 * MB2);   // [2][4096][256] = 4MB, dead after merge
    bf16*  t1    = (bf16*)(ws + 6 * MB2);   // reuses Ot region (4MB)

    float* statm = stats;
    float* statl = stats + 8192;

    k_qkv<<<dim3(64, 4, 3), 256, 0, stream>>>(x, y, Wq, bq, Wk, bk, Wv, bv, Qb, Kb, Vb);
    k_transpose<<<dim3(128, 8), 256, 0, stream>>>(Vb, Vt);
    k_flash<<<dim3(256, 2), 256, 0, stream>>>(Qb, Kb, Vt, Ot, statm, statl);
    k_merge<<<dim3(256), 256, 0, stream>>>(Ot, statm, statl, att);
    k_proj_ln<<<dim3(256), 256, 0, stream>>>(att, Wo, bo, lnw, lnb, zn);
    k_mlp1<<<dim3(64, 8), 256, 0, stream>>>(zn, W1, b1, t1);
    k_mlp2<<<dim3(64, 4), 256, 0, stream>>>(t1, W2, b2, x, out);
}

// Round 3
// 110.250 us; speedup vs baseline: 1.9499x; 1.9499x over previous
//
#include <hip/hip_runtime.h>
#include <hip/hip_bf16.h>
#include <math.h>

typedef __bf16 bf16;
typedef __bf16 bf16x4 __attribute__((ext_vector_type(4)));
typedef __bf16 bf16x8 __attribute__((ext_vector_type(8)));
typedef float f32x4 __attribute__((ext_vector_type(4)));
typedef unsigned short ushort8 __attribute__((ext_vector_type(8)));

#define MFMA16(a, b, c) __builtin_amdgcn_mfma_f32_16x16x32_bf16(a, b, c, 0, 0, 0)

__device__ inline bf16x8 frag2(bf16x4 a, bf16x4 b) {
    bf16x8 r;
    r[0] = a[0]; r[1] = a[1]; r[2] = a[2]; r[3] = a[3];
    r[4] = b[0]; r[5] = b[1]; r[6] = b[2]; r[7] = b[3];
    return r;
}

__device__ inline bf16x8 frag_from(const bf16* p0, const bf16* p1) {
    return frag2(*(const bf16x4*)p0, *(const bf16x4*)p1);
}

// ---------------------------------------------------------------------------
// Kernel 1: QKV projections.  out[i][o] = sum_c in[c][i] * W[o][c] + b[o]
// ---------------------------------------------------------------------------
__global__ __launch_bounds__(256) void k_qkv(
    const float* __restrict__ x, const float* __restrict__ y,
    const float* __restrict__ Wq, const float* __restrict__ bq,
    const float* __restrict__ Wk, const float* __restrict__ bk,
    const float* __restrict__ Wv, const float* __restrict__ bv,
    bf16* __restrict__ Qo, bf16* __restrict__ Ko, bf16* __restrict__ Vo)
{
    const int zi = blockIdx.z;
    const float* src  = (zi == 0) ? x : y;
    const float* W    = (zi == 0) ? Wq : (zi == 1 ? Wk : Wv);
    const float* bias = (zi == 0) ? bq : (zi == 1 ? bk : bv);
    bf16* dst         = (zi == 0) ? Qo : (zi == 1 ? Ko : Vo);

    const int i0 = blockIdx.x * 64;
    const int o0 = blockIdx.y * 64;
    const int t = threadIdx.x;
    const int lane = t & 63;
    const int w = t >> 6;
    const int wr = w >> 1, wc = w & 1;
    const int l16 = lane & 15, lg = lane >> 4;

    __shared__ bf16 As[64][40];   // [m][k]
    __shared__ bf16 Bs[64][40];   // [n][k]

    f32x4 acc[2][2] = {};

    for (int kc = 0; kc < 256; kc += 32) {
        __syncthreads();
        for (int p = 0; p < 2; ++p) {
            int e = t + 256 * p;          // 0..511
            int c = e >> 4, m0 = (e & 15) * 4;
            f32x4 v = *(const f32x4*)&src[(kc + c) * 4096 + i0 + m0];
            for (int j = 0; j < 4; ++j) As[m0 + j][c] = (bf16)v[j];
        }
        for (int p = 0; p < 2; ++p) {
            int e = t + 256 * p;
            int n = e >> 3, c0 = (e & 7) * 4;
            f32x4 v = *(const f32x4*)&W[(o0 + n) * 256 + kc + c0];
            bf16x4 b;
            for (int j = 0; j < 4; ++j) b[j] = (bf16)v[j];
            *(bf16x4*)&Bs[n][c0] = b;
        }
        __syncthreads();
        const int c0 = 4 * lg;
        bf16x8 af[2], bfr[2];
        for (int mi = 0; mi < 2; ++mi) {
            int m = 32 * wr + 16 * mi + l16;
            af[mi] = frag_from(&As[m][c0], &As[m][c0 + 16]);
        }
        for (int ni = 0; ni < 2; ++ni) {
            int n = 32 * wc + 16 * ni + l16;
            bfr[ni] = frag_from(&Bs[n][c0], &Bs[n][c0 + 16]);
        }
        for (int mi = 0; mi < 2; ++mi)
            for (int ni = 0; ni < 2; ++ni)
                acc[mi][ni] = MFMA16(af[mi], bfr[ni], acc[mi][ni]);
    }

    for (int mi = 0; mi < 2; ++mi)
        for (int ni = 0; ni < 2; ++ni) {
            int n = o0 + 32 * wc + 16 * ni + l16;
            float bv_ = bias[n];
            for (int i = 0; i < 4; ++i) {
                int m = i0 + 32 * wr + 16 * mi + 4 * lg + i;
                dst[m * 256 + n] = (bf16)(acc[mi][ni][i] + bv_);
            }
        }
}

// ---------------------------------------------------------------------------
// Kernel KF: pack K [4096][256] into fragment-linear Kf.
// Unit U (16B = 8 bf16): lane=U&63 (l16=U&15, lg=(U>>4)&3), kc=(U>>6)&7,
// c=(U>>9)&1, T=U>>10.  Contents: K[32T+16c+l16][32kc+4lg+{0..3}] then
// K[32T+16c+l16][32kc+16+4lg+{0..3}].
// ---------------------------------------------------------------------------
__global__ __launch_bounds__(256) void k_kfrag(
    const bf16* __restrict__ Kb, bf16* __restrict__ Kf)
{
    const unsigned U = blockIdx.x * 256 + threadIdx.x;   // 0..131071
    const int l16 = U & 15, lg = (U >> 4) & 3;
    const int kc = (U >> 6) & 7;
    const int c = (U >> 9) & 1;
    const int T = U >> 10;
    const int row = 32 * T + 16 * c + l16;
    const int col = 32 * kc + 4 * lg;
    bf16x4 v0 = *(const bf16x4*)(Kb + row * 256 + col);
    bf16x4 v1 = *(const bf16x4*)(Kb + row * 256 + col + 16);
    *(bf16x8*)(Kf + (size_t)U * 8) = frag2(v0, v1);
}

// ---------------------------------------------------------------------------
// Kernel VF: pack V [4096][256] into fragment-linear Vf (B-operand layout).
// Unit U: lane=U&63, ni=(U>>6)&15, T=U>>10.
// Contents: V[32T+4lg+{0..3}][16ni+l16] then V[32T+16+4lg+{0..3}][16ni+l16].
// One block per 32-key tile T; LDS-staged transpose.
// ---------------------------------------------------------------------------
__global__ __launch_bounds__(256) void k_vfrag(
    const bf16* __restrict__ Vb, bf16* __restrict__ Vf)
{
    __shared__ bf16 Vtile[32][256];
    const int T = blockIdx.x;          // 0..127
    const int t = threadIdx.x;
    for (int p = 0; p < 4; ++p) {
        int u = t + 256 * p;           // 0..1023
        int row = u >> 5, ch = u & 31;
        *(ushort8*)&Vtile[row][ch * 8] =
            *(const ushort8*)(Vb + (32 * T + row) * 256 + ch * 8);
    }
    __syncthreads();
    for (int p = 0; p < 4; ++p) {
        int u = t + 256 * p;
        int ni = u >> 6, lane = u & 63;
        int l16 = lane & 15, lg = lane >> 4;
        bf16x8 vals;
        for (int j = 0; j < 4; ++j) {
            vals[j]     = Vtile[4 * lg + j][16 * ni + l16];
            vals[4 + j] = Vtile[16 + 4 * lg + j][16 * ni + l16];
        }
        *(bf16x8*)(Vf + ((size_t)T * 1024 + u) * 8) = vals;
    }
}

// ---------------------------------------------------------------------------
// Kernel 2: flash attention, swapped QK^T (S^T = K x Q) so P is lane-local.
// Per block: 4 waves x 16 q-rows = 64 q; KV tiles of 32; 8-way KV split.
// K,V double-buffered in LDS from frag-linear global (coalesced 16B/lane),
// reg-staged issue-early/write-late. One barrier per tile.
// ---------------------------------------------------------------------------
__global__ __launch_bounds__(256, 2) void k_flash(
    const bf16* __restrict__ Qg, const bf16* __restrict__ Kf,
    const bf16* __restrict__ Vf, bf16* __restrict__ Ot,
    float* __restrict__ statm, float* __restrict__ statl)
{
    __shared__ bf16 Ks[2][8192];    // 16KB per buf, frag-linear tile
    __shared__ bf16 Vs[2][8192];

    const int t = threadIdx.x;
    const int lane = t & 63;
    const int w = t >> 6;
    const int l16 = lane & 15, lg = lane >> 4;
    const int qb = blockIdx.x;        // 0..63
    const int split = blockIdx.y;     // 0..7
    const int q0 = qb * 64 + w * 16;  // wave's q base
    const int T0 = split * 16;        // first 32-key tile of this split
    const int NT = 16;

    // Q fragments (B-operand), pre-scaled by 1/sqrt(256)=1/16 (exact in bf16)
    bf16x8 Qf[8];
#pragma unroll
    for (int kc = 0; kc < 8; ++kc) {
        const bf16* qp = Qg + (q0 + l16) * 256 + 32 * kc + 4 * lg;
        bf16x8 f = frag2(*(const bf16x4*)qp, *(const bf16x4*)(qp + 16));
#pragma unroll
        for (int j = 0; j < 8; ++j) f[j] = (bf16)((float)f[j] * 0.0625f);
        Qf[kc] = f;
    }

    float m_run = -1e30f, l_run = 0.f;
    f32x4 O[16] = {};   // O[ni][i] = O[q0+4lg+i][16ni+l16]

    ushort8 kst[4], vst[4];
    // prologue: load + write tile T0 into buf 0
#pragma unroll
    for (int j = 0; j < 4; ++j) {
        kst[j] = *(const ushort8*)(Kf + ((size_t)T0 * 1024 + j * 256 + t) * 8);
        vst[j] = *(const ushort8*)(Vf + ((size_t)T0 * 1024 + j * 256 + t) * 8);
    }
#pragma unroll
    for (int j = 0; j < 4; ++j) {
        *(ushort8*)&Ks[0][(j * 256 + t) * 8] = kst[j];
        *(ushort8*)&Vs[0][(j * 256 + t) * 8] = vst[j];
    }
    __syncthreads();

    int buf = 0;
    for (int tt = 0; tt < NT; ++tt) {
        if (tt < NT - 1) {           // issue next tile's loads early
            int T = T0 + tt + 1;
#pragma unroll
            for (int j = 0; j < 4; ++j) {
                kst[j] = *(const ushort8*)(Kf + ((size_t)T * 1024 + j * 256 + t) * 8);
                vst[j] = *(const ushort8*)(Vf + ((size_t)T * 1024 + j * 256 + t) * 8);
            }
        }

        // ---- QK^T (swapped): S^T chunks c=0,1; keys 16c+4lg+i, q=l16
        f32x4 S0 = {}, S1 = {};
        __builtin_amdgcn_s_setprio(1);
#pragma unroll
        for (int kc = 0; kc < 8; ++kc) {
            bf16x8 k0 = *(const bf16x8*)&Ks[buf][((0 * 8 + kc) * 64 + lane) * 8];
            bf16x8 k1 = *(const bf16x8*)&Ks[buf][((1 * 8 + kc) * 64 + lane) * 8];
            S0 = MFMA16(k0, Qf[kc], S0);
            S1 = MFMA16(k1, Qf[kc], S1);
        }
        __builtin_amdgcn_s_setprio(0);

        // ---- in-register online softmax (row q=l16, spread over lg groups)
        float p[8];
#pragma unroll
        for (int i = 0; i < 4; ++i) { p[i] = S0[i]; p[4 + i] = S1[i]; }
        float mx = p[0];
#pragma unroll
        for (int j = 1; j < 8; ++j) mx = fmaxf(mx, p[j]);
        mx = fmaxf(mx, __shfl_xor(mx, 16));
        mx = fmaxf(mx, __shfl_xor(mx, 32));
        float mn = fmaxf(m_run, mx);
        float corr = __expf(m_run - mn);
        m_run = mn;
        float sum = 0.f;
#pragma unroll
        for (int j = 0; j < 8; ++j) { p[j] = __expf(p[j] - mn); sum += p[j]; }
        sum += __shfl_xor(sum, 16);
        sum += __shfl_xor(sum, 32);
        l_run = l_run * corr + sum;

        bf16x8 pa;
#pragma unroll
        for (int j = 0; j < 8; ++j) pa[j] = (bf16)p[j];

        // ---- rescale O rows (q=4lg+i) by corr from lanes l16=4lg+i
        float cr[4];
#pragma unroll
        for (int i = 0; i < 4; ++i) cr[i] = __shfl(corr, 4 * lg + i);
#pragma unroll
        for (int ni = 0; ni < 16; ++ni)
#pragma unroll
            for (int i = 0; i < 4; ++i) O[ni][i] *= cr[i];

        // ---- PV: O += P @ V  (V B-frags lane-linear in LDS)
        __builtin_amdgcn_s_setprio(1);
#pragma unroll
        for (int ni = 0; ni < 16; ++ni) {
            bf16x8 vb = *(const bf16x8*)&Vs[buf][(ni * 64 + lane) * 8];
            O[ni] = MFMA16(pa, vb, O[ni]);
        }
        __builtin_amdgcn_s_setprio(0);

        if (tt < NT - 1) {           // write-late into other buffer
#pragma unroll
            for (int j = 0; j < 4; ++j) {
                *(ushort8*)&Ks[buf ^ 1][(j * 256 + t) * 8] = kst[j];
                *(ushort8*)&Vs[buf ^ 1][(j * 256 + t) * 8] = vst[j];
            }
        }
        __syncthreads();
        buf ^= 1;
    }

    // ---- normalized partial output + stats
    float il = 1.f / l_run;          // valid for q=l16
    float li[4];
#pragma unroll
    for (int i = 0; i < 4; ++i) li[i] = __shfl(il, 4 * lg + i);
#pragma unroll
    for (int ni = 0; ni < 16; ++ni)
#pragma unroll
        for (int i = 0; i < 4; ++i) {
            int q = q0 + 4 * lg + i;
            int d = 16 * ni + l16;
            Ot[((size_t)split * 4096 + q) * 256 + d] = (bf16)(O[ni][i] * li[i]);
        }
    if (lane < 16)
        if (true) {
            statm[split * 4096 + q0 + l16] = m_run;
            statl[split * 4096 + q0 + l16] = l_run;
        }
}

// ---------------------------------------------------------------------------
// Kernel M: merge 8 KV-splits.
// ---------------------------------------------------------------------------
__global__ __launch_bounds__(256) void k_merge(
    const bf16* __restrict__ Ot, const float* __restrict__ statm,
    const float* __restrict__ statl, bf16* __restrict__ att)
{
    const int t = threadIdx.x;
    const int q = blockIdx.x * 16 + (t >> 4);
    const int d0 = (t & 15) * 16;
    float ms[8], ls[8];
#pragma unroll
    for (int s = 0; s < 8; ++s) { ms[s] = statm[s * 4096 + q]; ls[s] = statl[s * 4096 + q]; }
    float M = ms[0];
#pragma unroll
    for (int s = 1; s < 8; ++s) M = fmaxf(M, ms[s]);
    float c[8], den = 0.f;
#pragma unroll
    for (int s = 0; s < 8; ++s) { c[s] = __expf(ms[s] - M) * ls[s]; den += c[s]; }
    float inv = 1.f / den;
#pragma unroll
    for (int s = 0; s < 8; ++s) c[s] *= inv;

    for (int h = 0; h < 2; ++h) {
        float acc[8] = {};
#pragma unroll
        for (int s = 0; s < 8; ++s) {
            bf16x8 v = *(const bf16x8*)(Ot + ((size_t)s * 4096 + q) * 256 + d0 + 8 * h);
#pragma unroll
            for (int j = 0; j < 8; ++j) acc[j] += c[s] * (float)v[j];
        }
        bf16x8 o;
#pragma unroll
        for (int j = 0; j < 8; ++j) o[j] = (bf16)acc[j];
        *(bf16x8*)(att + q * 256 + d0 + 8 * h) = o;
    }
}

// ---------------------------------------------------------------------------
// Kernel 3: z = att @ Wo^T + bo, then channel LayerNorm. BM=16, grid 256.
// ---------------------------------------------------------------------------
__global__ __launch_bounds__(256) void k_proj_ln(
    const bf16* __restrict__ att, const float* __restrict__ Wo,
    const float* __restrict__ bo, const float* __restrict__ ln_w,
    const float* __restrict__ ln_b, bf16* __restrict__ zn)
{
    __shared__ bf16 As[16][40];
    __shared__ bf16 Bs[256][40];
    __shared__ float psum[4][16], psq[4][16];
    __shared__ float mean_l[16], inv_l[16];

    const int t = threadIdx.x, lane = t & 63, w = t >> 6;
    const int l16 = lane & 15, lg = lane >> 4;
    const int q0 = blockIdx.x * 16;

    f32x4 acc[4] = {};
    for (int kc = 0; kc < 256; kc += 32) {
        __syncthreads();
        if (t < 64) {
            int r = t >> 2, u = t & 3;
            ushort8 v = *(const ushort8*)(att + (q0 + r) * 256 + kc + 8 * u);
            *(ushort8*)((char*)&As[r][0] + 16 * u) = v;
        }
        for (int p = 0; p < 8; ++p) {
            int e = t + 256 * p;          // 0..2047
            int n = e >> 3, c0 = (e & 7) * 4;
            f32x4 v = *(const f32x4*)&Wo[n * 256 + kc + c0];
            bf16x4 b;
            for (int j = 0; j < 4; ++j) b[j] = (bf16)v[j];
            *(bf16x4*)&Bs[n][c0] = b;
        }
        __syncthreads();
        bf16x8 af = frag_from(&As[l16][4 * lg], &As[l16][4 * lg + 16]);
        for (int ni = 0; ni < 4; ++ni) {
            int n = 64 * w + 16 * ni + l16;
            bf16x8 bfr = frag_from(&Bs[n][4 * lg], &Bs[n][4 * lg + 16]);
            acc[ni] = MFMA16(af, bfr, acc[ni]);
        }
    }

    float z[4][4];
    float rs[4] = {}, rq[4] = {};
    for (int ni = 0; ni < 4; ++ni) {
        int n = 64 * w + 16 * ni + l16;
        float b_ = bo[n];
        for (int i = 0; i < 4; ++i) {
            float v = acc[ni][i] + b_;
            z[ni][i] = v;
            rs[i] += v;
            rq[i] += v * v;
        }
    }
    for (int i = 0; i < 4; ++i) {
        float s = rs[i], q = rq[i];
        for (int msk = 1; msk <= 8; msk <<= 1) {
            s += __shfl_xor(s, msk);
            q += __shfl_xor(q, msk);
        }
        if (l16 == 0) { psum[w][4 * lg + i] = s; psq[w][4 * lg + i] = q; }
    }
    __syncthreads();
    if (t < 16) {
        float s = psum[0][t] + psum[1][t] + psum[2][t] + psum[3][t];
        float q = psq[0][t] + psq[1][t] + psq[2][t] + psq[3][t];
        float mean = s * (1.f / 256.f);
        float var = q * (1.f / 256.f) - mean * mean;
        mean_l[t] = mean;
        inv_l[t] = rsqrtf(var + 1e-6f);
    }
    __syncthreads();
    for (int ni = 0; ni < 4; ++ni) {
        int n = 64 * w + 16 * ni + l16;
        float g = ln_w[n], be = ln_b[n];
        for (int i = 0; i < 4; ++i) {
            int r = 4 * lg + i;
            float v = (z[ni][i] - mean_l[r]) * inv_l[r] * g + be;
            zn[(q0 + r) * 256 + n] = (bf16)v;
        }
    }
}

// ---------------------------------------------------------------------------
// Kernel 4: t1 = gelu(zn @ W1^T + b1)
// ---------------------------------------------------------------------------
__global__ __launch_bounds__(256) void k_mlp1(
    const bf16* __restrict__ zn, const float* __restrict__ W1,
    const float* __restrict__ b1, bf16* __restrict__ t1)
{
    __shared__ bf16 As[64][40];
    __shared__ bf16 Bs[64][40];
    const int t = threadIdx.x, lane = t & 63, w = t >> 6;
    const int l16 = lane & 15, lg = lane >> 4;
    const int wr = w >> 1, wc = w & 1;
    const int i0 = blockIdx.x * 64, n0 = blockIdx.y * 64;
    f32x4 acc[2][2] = {};
    for (int kc = 0; kc < 256; kc += 32) {
        __syncthreads();
        {
            int r = t >> 2, u = t & 3;
            ushort8 v = *(const ushort8*)(zn + (i0 + r) * 256 + kc + 8 * u);
            *(ushort8*)((char*)&As[r][0] + 16 * u) = v;
        }
        for (int p = 0; p < 2; ++p) {
            int e = t + 256 * p;
            int n = e >> 3, c0 = (e & 7) * 4;
            f32x4 v = *(const f32x4*)&W1[(n0 + n) * 256 + kc + c0];
            bf16x4 b;
            for (int j = 0; j < 4; ++j) b[j] = (bf16)v[j];
            *(bf16x4*)&Bs[n][c0] = b;
        }
        __syncthreads();
        bf16x8 af[2], bfr[2];
        for (int mi = 0; mi < 2; ++mi) {
            int m = 32 * wr + 16 * mi + l16;
            af[mi] = frag_from(&As[m][4 * lg], &As[m][4 * lg + 16]);
        }
        for (int ni = 0; ni < 2; ++ni) {
            int n = 32 * wc + 16 * ni + l16;
            bfr[ni] = frag_from(&Bs[n][4 * lg], &Bs[n][4 * lg + 16]);
        }
        for (int mi = 0; mi < 2; ++mi)
            for (int ni = 0; ni < 2; ++ni)
                acc[mi][ni] = MFMA16(af[mi], bfr[ni], acc[mi][ni]);
    }
    for (int ni = 0; ni < 2; ++ni) {
        int n = n0 + 32 * wc + 16 * ni + l16;
        float b_ = b1[n];
        for (int mi = 0; mi < 2; ++mi)
            for (int i = 0; i < 4; ++i) {
                int m = i0 + 32 * wr + 16 * mi + 4 * lg + i;
                float h = acc[mi][ni][i] + b_;
                float g = 0.5f * h * (1.f + erff(h * 0.70710678118f));
                t1[m * 512 + n] = (bf16)g;
            }
    }
}

// ---------------------------------------------------------------------------
// Kernel 5: t = t1 @ W2^T + b2; out[c][i] = x[c][i] + t[i][c]
// ---------------------------------------------------------------------------
__global__ __launch_bounds__(256) void k_mlp2(
    const bf16* __restrict__ t1, const float* __restrict__ W2,
    const float* __restrict__ b2, const float* __restrict__ x,
    float* __restrict__ out)
{
    __shared__ bf16 As[64][40];
    __shared__ bf16 Bs[64][40];
    __shared__ float T[64][65];
    const int t = threadIdx.x, lane = t & 63, w = t >> 6;
    const int l16 = lane & 15, lg = lane >> 4;
    const int wr = w >> 1, wc = w & 1;
    const int i0 = blockIdx.x * 64, n0 = blockIdx.y * 64;
    f32x4 acc[2][2] = {};
    for (int kc = 0; kc < 512; kc += 32) {
        __syncthreads();
        {
            int r = t >> 2, u = t & 3;
            ushort8 v = *(const ushort8*)(t1 + (i0 + r) * 512 + kc + 8 * u);
            *(ushort8*)((char*)&As[r][0] + 16 * u) = v;
        }
        for (int p = 0; p < 2; ++p) {
            int e = t + 256 * p;
            int n = e >> 3, c0 = (e & 7) * 4;
            f32x4 v = *(const f32x4*)&W2[(n0 + n) * 512 + kc + c0];
            bf16x4 b;
            for (int j = 0; j < 4; ++j) b[j] = (bf16)v[j];
            *(bf16x4*)&Bs[n][c0] = b;
        }
        __syncthreads();
        bf16x8 af[2], bfr[2];
        for (int mi = 0; mi < 2; ++mi) {
            int m = 32 * wr + 16 * mi + l16;
            af[mi] = frag_from(&As[m][4 * lg], &As[m][4 * lg + 16]);
        }
        for (int ni = 0; ni < 2; ++ni) {
            int n = 32 * wc + 16 * ni + l16;
            bfr[ni] = frag_from(&Bs[n][4 * lg], &Bs[n][4 * lg + 16]);
        }
        for (int mi = 0; mi < 2; ++mi)
            for (int ni = 0; ni < 2; ++ni)
                acc[mi][ni] = MFMA16(af[mi], bfr[ni], acc[mi][ni]);
    }
    for (int ni = 0; ni < 2; ++ni) {
        int nn = 32 * wc + 16 * ni + l16;
        float b_ = b2[n0 + nn];
        for (int mi = 0; mi < 2; ++mi)
            for (int i = 0; i < 4; ++i) {
                int mloc = 32 * wr + 16 * mi + 4 * lg + i;
                T[nn][mloc] = acc[mi][ni][i] + b_;
            }
    }
    __syncthreads();
    for (int p = 0; p < 16; ++p) {
        int e = t + 256 * p;
        int nn = e >> 6, mm = e & 63;
        int c = n0 + nn, m = i0 + mm;
        out[c * 4096 + m] = x[c * 4096 + m] + T[nn][mm];
    }
}

// ---------------------------------------------------------------------------
extern "C" void kernel_launch(void* const* d_in, const int* in_sizes, int n_in,
                              void* d_out, int out_size, void* d_ws, size_t ws_size,
                              hipStream_t stream) {
    (void)in_sizes; (void)n_in; (void)out_size; (void)ws_size;
    const float* x   = (const float*)d_in[0];
    const float* y   = (const float*)d_in[1];
    const float* Wq  = (const float*)d_in[2];
    const float* bq  = (const float*)d_in[3];
    const float* Wk  = (const float*)d_in[4];
    const float* bk  = (const float*)d_in[5];
    const float* Wv  = (const float*)d_in[6];
    const float* bv  = (const float*)d_in[7];
    const float* Wo  = (const float*)d_in[8];
    const float* bo  = (const float*)d_in[9];
    const float* lnw = (const float*)d_in[10];
    const float* lnb = (const float*)d_in[11];
    const float* W1  = (const float*)d_in[12];
    const float* b1  = (const float*)d_in[13];
    const float* W2  = (const float*)d_in[14];
    const float* b2  = (const float*)d_in[15];
    float* out = (float*)d_out;

    char* ws = (char*)d_ws;
    const size_t MB = 1u << 20;
    // Layout (peak 22.25 MB):
    //  [0,2)    Qb      -> att after flash
    //  [2,4)    Kf      -> zn after flash
    //  [4,6)    Vf
    //  [6,6.25) stats (statm 128KB + statl 128KB)
    //  [6.25, 22.25) Ot (16MB); Kb/Vb live here pre-flash; t1 here post-merge
    bf16*  Qb    = (bf16*)(ws + 0 * MB);
    bf16*  Kf    = (bf16*)(ws + 2 * MB);
    bf16*  Vf    = (bf16*)(ws + 4 * MB);
    float* statm = (float*)(ws + 6 * MB);
    float* statl = (float*)(ws + 6 * MB + 128 * 1024);
    char*  big   = ws + 6 * MB + 256 * 1024;
    bf16*  Ot    = (bf16*)big;
    bf16*  Kb    = (bf16*)big;                 // pre-flash only
    bf16*  Vb    = (bf16*)(big + 2 * MB);      // pre-flash only
    bf16*  t1    = (bf16*)big;                 // post-merge only
    bf16*  att   = (bf16*)(ws + 0 * MB);       // post-flash (Qb dead)
    bf16*  zn    = (bf16*)(ws + 2 * MB);       // post-flash (Kf dead)

    k_qkv<<<dim3(64, 4, 3), 256, 0, stream>>>(x, y, Wq, bq, Wk, bk, Wv, bv, Qb, Kb, Vb);
    k_kfrag<<<dim3(512), 256, 0, stream>>>(Kb, Kf);
    k_vfrag<<<dim3(128), 256, 0, stream>>>(Vb, Vf);
    k_flash<<<dim3(64, 8), 256, 0, stream>>>(Qb, Kf, Vf, Ot, statm, statl);
    k_merge<<<dim3(256), 256, 0, stream>>>(Ot, statm, statl, att);
    k_proj_ln<<<dim3(256), 256, 0, stream>>>(att, Wo, bo, lnw, lnb, zn);
    k_mlp1<<<dim3(64, 8), 256, 0, stream>>>(zn, W1, b1, t1);
    k_mlp2<<<dim3(64, 4), 256, 0, stream>>>(t1, W2, b2, x, out);
}